// Round 16
// baseline (647.283 us; speedup 1.0000x reference)
//
#include <hip/hip_runtime.h>
#include <hip/hip_bf16.h>
#include <math.h>

// ProGAT: B=32, S=512, K=21, F_in=26, E=256, R=3, T=2
// Round 16: launch-count attack (18 -> 12 dispatches). cvt folded into embed launch;
// tail mega-fused: one 32-block sgru_tail (wave-parallel dots, NOT round-8's serial
// per-thread dots) replaces wpool+sctx_mm+sgru_mm x2+sgru_gate x2.

#define NEGC (-9.0e8f)

typedef __attribute__((ext_vector_type(8))) short bf16x8;
typedef __attribute__((ext_vector_type(4))) float f32x4;

__device__ __forceinline__ ushort f2bf(float x) {
    union { float f; unsigned u; } v; v.f = x;
    unsigned r = v.u + 0x7FFF + ((v.u >> 16) & 1);
    return (ushort)(r >> 16);
}
__device__ __forceinline__ float bf2f(ushort u) {
    union { unsigned u; float f; } v; v.u = ((unsigned)u) << 16;
    return v.f;
}
__device__ __forceinline__ float sigm_fast(float x) {
    return 1.f / (1.f + __expf(-x));
}
__device__ __forceinline__ float tanh_fast(float x) {
    return 1.f - 2.f / (__expf(2.f * x) + 1.f);
}
__device__ __forceinline__ float elu_fast(float x) {
    return x > 0.f ? x : (__expf(x) - 1.f);
}
__device__ __forceinline__ bf16x8 relu_bf8(bf16x8 v) {
    bf16x8 r;
#pragma unroll
    for (int i = 0; i < 8; ++i)
        r[i] = (v[i] & (short)0x8000) ? (short)0 : v[i];
    return r;
}

typedef const __attribute__((address_space(1))) void gvoid_t;
typedef __attribute__((address_space(3))) void lvoid_t;

// ---------------- merged cvt (blocks 0..cvtb-1) + embed (rest) ----------------
__global__ __launch_bounds__(256) void cvt_embed_kernel(
    const float* __restrict__ s0, ushort* __restrict__ d0, int n0,
    const float* __restrict__ s1, ushort* __restrict__ d1, int n1,
    const float* __restrict__ s2, ushort* __restrict__ d2, int n2,
    int cvtb,
    const float* __restrict__ amino, const float* __restrict__ embW,
    const float* __restrict__ embB, const float* __restrict__ neighW,
    const float* __restrict__ neighB, const float* __restrict__ alignW,
    ushort* __restrict__ h_bf, ushort* __restrict__ nf_bf,
    float* __restrict__ ca, float* __restrict__ cb)
{
    if ((int)blockIdx.x < cvtb) {
        int i = blockIdx.x * 256 + threadIdx.x;
        const float* s; ushort* dst; int l;
        if (i < n0) { s = s0; dst = d0; l = i; }
        else if (i < n0 + n1) { s = s1; dst = d1; l = i - n0; }
        else if (i < n0 + n1 + n2) { s = s2; dst = d2; l = i - n0 - n1; }
        else return;
        float4 v = *reinterpret_cast<const float4*>(s + (size_t)l * 4);
        ushort4 o; o.x = f2bf(v.x); o.y = f2bf(v.y); o.z = f2bf(v.z); o.w = f2bf(v.w);
        *reinterpret_cast<ushort4*>(dst + (size_t)l * 4) = o;
        return;
    }
    const int FIN = 26, FPAD = 28, ROWS = 64;
    __shared__ __align__(16) float xs[ROWS][FPAD];
    __shared__ float red1[ROWS][4];
    __shared__ float red2[ROWS][4];
    int tid = threadIdx.x;
    int lane = tid & 63, wv = tid >> 6;
    float wE[FPAD], wN[FPAD];
#pragma unroll
    for (int f = 0; f < FIN; ++f) {
        wE[f] = embW[tid * FIN + f];
        wN[f] = neighW[tid * FIN + f];
    }
    wE[26] = wE[27] = wN[26] = wN[27] = 0.f;
    float b1 = embB[tid], b2 = neighB[tid];
    float w1t = alignW[tid], w2t = alignW[256 + tid];
    int row0 = (blockIdx.x - cvtb) * ROWS;
    for (int idx = tid; idx < ROWS * FPAD; idx += 256) {
        int r = idx / FPAD, f = idx - r * FPAD;
        xs[r][f] = (f < FIN) ? amino[(size_t)(row0 + r) * FIN + f] : 0.f;
    }
    __syncthreads();
    for (int r = 0; r < ROWS; ++r) {
        const float4* x4 = reinterpret_cast<const float4*>(xs[r]);
        float a = b1, c = b2;
#pragma unroll
        for (int q = 0; q < 7; ++q) {
            float4 x = x4[q];
            a = fmaf(x.x, wE[4 * q], a);     c = fmaf(x.x, wN[4 * q], c);
            a = fmaf(x.y, wE[4 * q + 1], a); c = fmaf(x.y, wN[4 * q + 1], c);
            a = fmaf(x.z, wE[4 * q + 2], a); c = fmaf(x.z, wN[4 * q + 2], c);
            a = fmaf(x.w, wE[4 * q + 3], a); c = fmaf(x.w, wN[4 * q + 3], c);
        }
        a = a > 0.f ? a : 0.01f * a;
        c = c > 0.f ? c : 0.01f * c;
        size_t idx = (size_t)(row0 + r) * 256 + tid;
        h_bf[idx] = f2bf(a);
        nf_bf[idx] = f2bf(c);
        float p1 = a * w1t, p2 = c * w2t;
#pragma unroll
        for (int off = 32; off > 0; off >>= 1) {
            p1 += __shfl_down(p1, off);
            p2 += __shfl_down(p2, off);
        }
        if (lane == 0) { red1[r][wv] = p1; red2[r][wv] = p2; }
    }
    __syncthreads();
    if (tid < ROWS)
        ca[row0 + tid] = red1[tid][0] + red1[tid][1] + red1[tid][2] + red1[tid][3];
    else if (tid < 2 * ROWS) {
        int r = tid - ROWS;
        cb[row0 + r] = red2[r][0] + red2[r][1] + red2[r][2] + red2[r][3];
    }
}

// ---------------- bf16 MFMA GEMM (attend) + optional per-row dots over A0 ----------
template<bool RELUA>
__global__ __launch_bounds__(256) void gemm_dual_kernel(
    const ushort* __restrict__ A0, const ushort* __restrict__ W0,
    const float* __restrict__ b0, ushort* __restrict__ C0, int n0t,
    int K,
    const float* __restrict__ dw1, const float* __restrict__ dw2,
    float* __restrict__ dout1, float* __restrict__ dout2)
{
    __shared__ __align__(16) short As[128 * 32];
    __shared__ __align__(16) short Bs[128 * 32];
    int nwg = gridDim.x;
    int q = nwg >> 3;
    int flat = blockIdx.x;
    int sw = (flat & 7) * q + (flat >> 3);
    int bmi = sw / n0t, bni = sw - bmi * n0t;
    const ushort* A = A0; const ushort* W = W0; const float* bias = b0;
    ushort* C = C0; int N = n0t << 7; int bn = bni << 7;
    int bm = bmi << 7;

    int tid = threadIdx.x;
    int lane = tid & 63;
    int w = tid >> 6;
    int wr = w >> 1, wc = w & 1;
    bool dots = (dout1 != nullptr) && (bni == 0);

    f32x4 acc[4][4];
#pragma unroll
    for (int m = 0; m < 4; ++m)
#pragma unroll
        for (int n = 0; n < 4; ++n) acc[m][n] = (f32x4){0.f, 0.f, 0.f, 0.f};
    float p1 = 0.f, p2 = 0.f;

    for (int k0 = 0; k0 < K; k0 += 32) {
#pragma unroll
        for (int i = 0; i < 2; ++i) {
            int e = w * 1024 + i * 512 + lane * 8;
            int r = e >> 5, c = e & 31;
            const ushort* ga = A + (size_t)(bm + r) * K + (k0 + c);
            const ushort* gw = W + (size_t)(bn + r) * K + (k0 + c);
            __builtin_amdgcn_global_load_lds((gvoid_t*)ga, (lvoid_t*)&As[w * 1024 + i * 512], 16, 0, 0);
            __builtin_amdgcn_global_load_lds((gvoid_t*)gw, (lvoid_t*)&Bs[w * 1024 + i * 512], 16, 0, 0);
        }
        __syncthreads();
        bf16x8 af[4], bw[4];
        int ra = wr * 64 + (lane & 15);
        int rb = wc * 64 + (lane & 15);
        int kc = (lane >> 4) * 8;
#pragma unroll
        for (int m = 0; m < 4; ++m) {
            af[m] = *reinterpret_cast<const bf16x8*>(&As[(ra + m * 16) * 32 + kc]);
            if (RELUA) af[m] = relu_bf8(af[m]);
        }
#pragma unroll
        for (int n = 0; n < 4; ++n)
            bw[n] = *reinterpret_cast<const bf16x8*>(&Bs[(rb + n * 16) * 32 + kc]);
#pragma unroll
        for (int m = 0; m < 4; ++m)
#pragma unroll
            for (int n = 0; n < 4; ++n)
                acc[m][n] = __builtin_amdgcn_mfma_f32_16x16x32_bf16(af[m], bw[n], acc[m][n], 0, 0, 0);
        if (dots) {
            int drow = tid >> 1, kh = (tid & 1) << 4;
            const short* ar = &As[drow * 32 + kh];
#pragma unroll
            for (int c = 0; c < 16; ++c) {
                float av = bf2f((ushort)ar[c]);
                if (RELUA) av = fmaxf(av, 0.f);
                p1 = fmaf(av, dw1[k0 + kh + c], p1);
                p2 = fmaf(av, dw2[k0 + kh + c], p2);
            }
        }
        __syncthreads();
    }

    if (dots) {
        p1 += __shfl_xor(p1, 1);
        p2 += __shfl_xor(p2, 1);
        if ((tid & 1) == 0) {
            dout1[bm + (tid >> 1)] = p1;
            dout2[bm + (tid >> 1)] = p2;
        }
    }

    int cr0 = bm + wr * 64 + ((lane >> 4) * 4);
    int cc0 = bn + wc * 64 + (lane & 15);
#pragma unroll
    for (int n = 0; n < 4; ++n) {
        int col = cc0 + n * 16;
        float bv = bias[col];
#pragma unroll
        for (int m = 0; m < 4; ++m) {
            int row0 = cr0 + m * 16;
#pragma unroll
            for (int j = 0; j < 4; ++j) {
                float v = acc[m][n][j] + bv;
                C[(size_t)(row0 + j) * N + col] = f2bf(v);
            }
        }
    }
}

// ---------------- fused GRU GEMM+gate v2 (64x64 tile, double-buffered h) ------------
template<bool TAIL>
__global__ __launch_bounds__(256) void gru_fused_kernel(
    const ushort* __restrict__ ctx, const ushort* __restrict__ wih,
    const float* __restrict__ bih, const ushort* __restrict__ whh,
    const float* __restrict__ bhh,
    const ushort* __restrict__ h_in, ushort* __restrict__ h_out,
    const float* __restrict__ mask, float* __restrict__ pool_part,
    const float* __restrict__ dsw, float* __restrict__ scor_part, int BS)
{
    __shared__ __align__(16) short lds[16384];   // 8 panels x [64][32]
    int flat = blockIdx.x;                       // 1024
    int sw = (flat & 7) * 128 + (flat >> 3);     // bijective XCD swizzle
    int bmi = sw >> 2, ct = sw & 3;
    int bm = bmi << 6;
    int tid = threadIdx.x;
    int lane = tid & 63;
    int w = tid >> 6;
    int wr = w >> 1, wc = w & 1;

    f32x4 acc[6][2][2];
#pragma unroll
    for (int qq = 0; qq < 6; ++qq)
#pragma unroll
        for (int m = 0; m < 2; ++m)
#pragma unroll
            for (int n = 0; n < 2; ++n) acc[qq][m][n] = (f32x4){0.f, 0.f, 0.f, 0.f};

    int srow = tid >> 2, scol = (tid & 3) << 3;
    int ldst = (tid & 0xC0) * 8;
    for (int k0 = 0; k0 < 256; k0 += 32) {
        {
            const ushort* s0 = ctx  + (size_t)(bm + srow) * 256 + k0 + scol;
            const ushort* s1 = h_in + (size_t)(bm + srow) * 256 + k0 + scol;
            __builtin_amdgcn_global_load_lds((gvoid_t*)s0, (lvoid_t*)&lds[ldst], 16, 0, 0);
            __builtin_amdgcn_global_load_lds((gvoid_t*)s1, (lvoid_t*)&lds[2048 + ldst], 16, 0, 0);
#pragma unroll
            for (int qq = 0; qq < 6; ++qq) {
                const ushort* wb = (qq < 3) ? wih : whh;
                int slice = (qq < 3) ? qq : qq - 3;
                const ushort* sv = wb + (size_t)(slice * 256 + ct * 64 + srow) * 256 + k0 + scol;
                __builtin_amdgcn_global_load_lds((gvoid_t*)sv,
                    (lvoid_t*)&lds[(2 + qq) * 2048 + ldst], 16, 0, 0);
            }
        }
        __syncthreads();
        int rl = lane & 15;
        int kc = (lane >> 4) * 8;
        bf16x8 a_c[2], a_h[2];
#pragma unroll
        for (int m = 0; m < 2; ++m) {
            a_c[m] = *reinterpret_cast<const bf16x8*>(&lds[(wr * 32 + m * 16 + rl) * 32 + kc]);
            a_h[m] = *reinterpret_cast<const bf16x8*>(&lds[2048 + (wr * 32 + m * 16 + rl) * 32 + kc]);
        }
#pragma unroll
        for (int qq = 0; qq < 6; ++qq) {
            bf16x8 bw[2];
#pragma unroll
            for (int n = 0; n < 2; ++n)
                bw[n] = *reinterpret_cast<const bf16x8*>(
                    &lds[(2 + qq) * 2048 + (wc * 32 + n * 16 + rl) * 32 + kc]);
#pragma unroll
            for (int m = 0; m < 2; ++m)
#pragma unroll
                for (int n = 0; n < 2; ++n)
                    acc[qq][m][n] = __builtin_amdgcn_mfma_f32_16x16x32_bf16(
                        (qq < 3) ? a_c[m] : a_h[m], bw[n], acc[qq][m][n], 0, 0, 0);
        }
        __syncthreads();
    }

    int rl = lane & 15;
    int r0 = (lane >> 4) * 4;
    float mv[2][4];
    float dswv[2];
    if (TAIL) {
        int b_ = bm >> 9;
        int sbase = bm & 511;
#pragma unroll
        for (int m = 0; m < 2; ++m)
#pragma unroll
            for (int j = 0; j < 4; ++j)
                mv[m][j] = mask[b_ * 512 + sbase + wr * 32 + m * 16 + r0 + j];
#pragma unroll
        for (int n = 0; n < 2; ++n)
            dswv[n] = dsw[ct * 64 + wc * 32 + n * 16 + rl];
    }
    float pm[2] = {0.f, 0.f};
    float ps[2][4] = {{0.f, 0.f, 0.f, 0.f}, {0.f, 0.f, 0.f, 0.f}};

#pragma unroll
    for (int n = 0; n < 2; ++n) {
        int col = ct * 64 + wc * 32 + n * 16 + rl;
        float bir = bih[col], biz = bih[256 + col], bin = bih[512 + col];
        float bhr = bhh[col], bhz = bhh[256 + col], bhn = bhh[512 + col];
#pragma unroll
        for (int m = 0; m < 2; ++m) {
            int row0 = bm + wr * 32 + m * 16 + r0;
#pragma unroll
            for (int j = 0; j < 4; ++j) {
                size_t idx = (size_t)(row0 + j) * 256 + col;
                float r = sigm_fast(acc[0][m][n][j] + bir + acc[3][m][n][j] + bhr);
                float z = sigm_fast(acc[1][m][n][j] + biz + acc[4][m][n][j] + bhz);
                float nn = tanh_fast(acc[2][m][n][j] + bin + r * (acc[5][m][n][j] + bhn));
                float hold = bf2f(h_in[idx]);
                float hh = (1.f - z) * nn + z * hold;
                ushort hb = f2bf(hh);
                h_out[idx] = hb;
                if (TAIL) {
                    float a = fmaxf(bf2f(hb), 0.f);
                    pm[n] = fmaf(a, mv[m][j], pm[n]);
                    ps[m][j] = fmaf(a, dswv[n], ps[m][j]);
                }
            }
        }
    }

    if (TAIL) {
#pragma unroll
        for (int n = 0; n < 2; ++n) {
            float p = pm[n];
            p += __shfl_xor(p, 16);
            p += __shfl_xor(p, 32);
            if (lane < 16) {
                int b_ = bm >> 9;
                int sc = ((bm & 511) >> 5) + wr;
                int col = ct * 64 + wc * 32 + n * 16 + rl;
                pool_part[((size_t)b_ * 16 + sc) * 256 + col] = p;
            }
        }
#pragma unroll
        for (int m = 0; m < 2; ++m)
#pragma unroll
            for (int j = 0; j < 4; ++j) {
                float p = ps[m][j];
                p += __shfl_xor(p, 1);
                p += __shfl_xor(p, 2);
                p += __shfl_xor(p, 4);
                p += __shfl_xor(p, 8);
                if (rl == 0) {
                    int row = bm + wr * 32 + m * 16 + r0 + j;
                    scor_part[(size_t)(ct * 2 + wc) * BS + row] = p;
                }
            }
    }
}

// attn: 4 rows/block, one wave per row, BRANCHLESS bf16 gather
__global__ __launch_bounds__(256) void attn_kernel(
    const int* __restrict__ deg, const float* __restrict__ ca,
    const float* __restrict__ cbrow, const ushort* __restrict__ act_t,
    const float* __restrict__ alignB, int d,
    ushort* __restrict__ context_bf, int S)
{
    const int KNB = 21;
    int raw = blockIdx.x;
    int bid = (raw & 7) * 512 + (raw >> 3);
    int bs0 = bid * 4;
    int b = bs0 >> 9;
    int tid = threadIdx.x;
    int wv = tid >> 6, lane = tid & 63;
    int bs = bs0 + wv;
    __shared__ float ss[4][KNB];
    __shared__ int   sj[4][KNB];
    if (lane < KNB) {
        int j = deg[bs * KNB + lane];
        float cbv = (j >= 0) ? cbrow[b * S + j] : 0.f;
        float sc = ca[bs] + cbv + alignB[d];
        sc = sc > 0.f ? sc : 0.01f * sc;
        if (j < 0) sc += NEGC;
        sj[wv][lane] = j;
        ss[wv][lane] = sc;
    }
    __syncthreads();
    float mx = -3.4e38f;
#pragma unroll
    for (int k = 0; k < KNB; ++k) mx = fmaxf(mx, ss[wv][k]);
    float se[KNB];
    int js[KNB];
    float sum = 0.f;
#pragma unroll
    for (int k = 0; k < KNB; ++k) {
        int j = sj[wv][k];
        float e = __expf(ss[wv][k] - mx);
        sum += e;
        se[k] = (j >= 0) ? e : 0.f;
        js[k] = (j >= 0) ? j : 0;
    }
    float inv = 1.f / sum;
    const ushort* base = act_t + (size_t)b * S * 256 + lane * 4;
    float a0 = 0.f, a1 = 0.f, a2 = 0.f, a3 = 0.f;
#pragma unroll
    for (int k = 0; k < KNB; ++k) {
        ushort4 v = *reinterpret_cast<const ushort4*>(base + (size_t)js[k] * 256);
        float wk = se[k];
        a0 = fmaf(wk, bf2f(v.x), a0);
        a1 = fmaf(wk, bf2f(v.y), a1);
        a2 = fmaf(wk, bf2f(v.z), a2);
        a3 = fmaf(wk, bf2f(v.w), a3);
    }
    ushort4 o;
    o.x = f2bf(elu_fast(a0 * inv));
    o.y = f2bf(elu_fast(a1 * inv));
    o.z = f2bf(elu_fast(a2 * inv));
    o.w = f2bf(elu_fast(a3 * inv));
    *reinterpret_cast<ushort4*>(&context_bf[(size_t)bs * 256 + lane * 4]) = o;
}

// fused: combine pool partials -> seqfeat + moldot; praw from scor_part (8 slices);
// softmax over S -> wbuf; masked weight sum -> wsumb.
__global__ __launch_bounds__(256) void seqpool_sm_kernel(
    const float* __restrict__ partial, const float* __restrict__ saW,
    const float* __restrict__ scor_part, const float* __restrict__ sab,
    const float* __restrict__ mask,
    float* __restrict__ seqfeat, float* __restrict__ wout,
    float* __restrict__ wsumb, int NC, int S, int BS)
{
    int b = blockIdx.x, tid = threadIdx.x;
    int lane = tid & 63, wv = tid >> 6;
    __shared__ float red[4];
    __shared__ float sw[512];
    __shared__ float r1[4], r2[4], r3[4];
    __shared__ float smd;
    float acc = 0.f;
    for (int c = 0; c < NC; ++c)
        acc += partial[((size_t)b * NC + c) * 256 + tid];
    seqfeat[b * 256 + tid] = acc;
    float am = fmaxf(acc, 0.f);
    float p = am * saW[tid];
#pragma unroll
    for (int off = 32; off > 0; off >>= 1) p += __shfl_down(p, off);
    if (lane == 0) red[wv] = p;
    __syncthreads();
    if (tid == 0) smd = red[0] + red[1] + red[2] + red[3];
    __syncthreads();
    float md = smd, sb = sab[0];
    float lm = -3.4e38f;
    for (int s = tid; s < S; s += 256) {
        int row = b * S + s;
        float praw = 0.f;
#pragma unroll
        for (int sl = 0; sl < 8; ++sl) praw += scor_part[(size_t)sl * BS + row];
        float sc = md + praw + sb;
        sc = sc > 0.f ? sc : 0.01f * sc;
        if (mask[row] == 0.f) sc += NEGC;
        sw[s] = sc;
        lm = fmaxf(lm, sc);
    }
#pragma unroll
    for (int off = 32; off > 0; off >>= 1) lm = fmaxf(lm, __shfl_down(lm, off));
    if (lane == 0) r1[wv] = lm;
    __syncthreads();
    float mx = fmaxf(fmaxf(r1[0], r1[1]), fmaxf(r1[2], r1[3]));
    float ls = 0.f, ms = 0.f;
    for (int s = tid; s < S; s += 256) {
        float e = __expf(sw[s] - mx);
        float em = e * mask[b * S + s];
        sw[s] = em;
        ls += e;
        ms += em;
    }
#pragma unroll
    for (int off = 32; off > 0; off >>= 1) {
        ls += __shfl_down(ls, off);
        ms += __shfl_down(ms, off);
    }
    if (lane == 0) { r2[wv] = ls; r3[wv] = ms; }
    __syncthreads();
    float inv = 1.f / (r2[0] + r2[1] + r2[2] + r2[3]);
    if (tid == 0) wsumb[b] = (r3[0] + r3[1] + r3[2] + r3[3]) * inv;
    for (int s = tid; s < S; s += 256)
        wout[b * S + s] = sw[s] * inv;
}

// ---------------- tail mega-kernel: V-pool + sctx matvec + 2-step small GRU --------
// One block per b. Wave-parallel dots throughout (round-8's serial dots avoided).
__global__ __launch_bounds__(256) void sgru_tail_kernel(
    const float* __restrict__ wbuf, const ushort* __restrict__ h,
    const float* __restrict__ seqAttW, const float* __restrict__ seqAttB,
    const float* __restrict__ wsumb, const float* __restrict__ seqf,
    const float* __restrict__ sWih, const float* __restrict__ sWhh,
    const float* __restrict__ sBih, const float* __restrict__ sBhh,
    float* __restrict__ out, int S)
{
    __shared__ float V[256];
    __shared__ float x[256];
    __shared__ float hs[256];
    __shared__ float giL[768];
    __shared__ float ghL[768];
    int b = blockIdx.x, tid = threadIdx.x;
    int lane = tid & 63, wv = tid >> 6;

    // V = sum_s wbuf[b,s] * relu(h[b,s,tid])   (coalesced row loads)
    float acc = 0.f;
    const ushort* hb = h + (size_t)b * S * 256;
    const float* wb = wbuf + b * S;
    for (int s = 0; s < S; ++s)
        acc = fmaf(wb[s], fmaxf(bf2f(hb[(size_t)s * 256 + tid]), 0.f), acc);
    V[tid] = acc;
    hs[tid] = seqf[b * 256 + tid];
    __syncthreads();

    // x[col] = elu(V . seqAttW[col] + wsumb[b]*seqAttB[col]); 64 cols per wave
    float wsb = wsumb[b];
    for (int col = wv * 64; col < wv * 64 + 64; ++col) {
        const float* wr_ = seqAttW + (size_t)col * 256;
        float p = 0.f;
#pragma unroll
        for (int i = 0; i < 4; ++i)
            p = fmaf(V[lane + 64 * i], wr_[lane + 64 * i], p);
#pragma unroll
        for (int off = 32; off > 0; off >>= 1) p += __shfl_down(p, off);
        if (lane == 0) x[col] = elu_fast(p + wsb * seqAttB[col]);
    }
    __syncthreads();

    // gi[j] = x . sWih[j] + sBih[j]
    for (int j = wv; j < 768; j += 4) {
        const float* wr_ = sWih + (size_t)j * 256;
        float p = 0.f;
#pragma unroll
        for (int i = 0; i < 4; ++i)
            p = fmaf(x[lane + 64 * i], wr_[lane + 64 * i], p);
#pragma unroll
        for (int off = 32; off > 0; off >>= 1) p += __shfl_down(p, off);
        if (lane == 0) giL[j] = p + sBih[j];
    }
    __syncthreads();

    float hn = 0.f;
    for (int t = 0; t < 2; ++t) {
        for (int j = wv; j < 768; j += 4) {
            const float* wr_ = sWhh + (size_t)j * 256;
            float p = 0.f;
#pragma unroll
            for (int i = 0; i < 4; ++i)
                p = fmaf(hs[lane + 64 * i], wr_[lane + 64 * i], p);
#pragma unroll
            for (int off = 32; off > 0; off >>= 1) p += __shfl_down(p, off);
            if (lane == 0) ghL[j] = p + sBhh[j];
        }
        __syncthreads();
        float r = sigm_fast(giL[tid] + ghL[tid]);
        float z = sigm_fast(giL[256 + tid] + ghL[256 + tid]);
        float n = tanh_fast(giL[512 + tid] + r * ghL[512 + tid]);
        hn = (1.f - z) * n + z * hs[tid];
        __syncthreads();
        hs[tid] = hn;
        __syncthreads();
    }
    out[b * 256 + tid] = fmaxf(hn, 0.f);
}

extern "C" void kernel_launch(void* const* d_in, const int* in_sizes, int n_in,
                              void* d_out, int out_size, void* d_ws, size_t ws_size,
                              hipStream_t stream)
{
    const float* amino   = (const float*)d_in[0];
    const int*   deg     = (const int*)  d_in[1];
    const float* mask    = (const float*)d_in[2];
    const float* embW    = (const float*)d_in[3];
    const float* embB    = (const float*)d_in[4];
    const float* neighW  = (const float*)d_in[5];
    const float* neighB  = (const float*)d_in[6];
    const float* alignW  = (const float*)d_in[7];
    const float* alignB  = (const float*)d_in[8];
    const float* attendW = (const float*)d_in[9];
    const float* attendB = (const float*)d_in[10];
    const float* gruWih  = (const float*)d_in[11];
    const float* gruWhh  = (const float*)d_in[12];
    const float* gruBih  = (const float*)d_in[13];
    const float* gruBhh  = (const float*)d_in[14];
    const float* saW     = (const float*)d_in[15];
    const float* saB     = (const float*)d_in[16];
    const float* seqAttW = (const float*)d_in[17];
    const float* seqAttB = (const float*)d_in[18];
    const float* sWih    = (const float*)d_in[19];
    const float* sWhh    = (const float*)d_in[20];
    const float* sBih    = (const float*)d_in[21];
    const float* sBhh    = (const float*)d_in[22];
    float* out = (float*)d_out;

    const int B = 32, S = 512;
    const int BS = B * S;                 // 16384
    const size_t N1 = (size_t)BS * 256;   // 4194304

    ushort* hA     = (ushort*)d_ws;              // N1 (bf16 GRU state, ping)
    ushort* hB     = hA + N1;                    // N1 (pong)
    ushort* nb_bf  = hB + N1;                    // N1 (nf round 0, then context)
    ushort* att_bf = nb_bf + N1;                 // N1 (act_t)
    ushort* attW_bf = att_bf + N1;               // 3*256*256
    ushort* wih_bf  = attW_bf + 3 * 256 * 256;   // 3*768*256
    ushort* whh_bf  = wih_bf + 3 * 768 * 256;
    float* smalls = (float*)(whh_bf + 3 * 768 * 256);
    float* ca    = smalls;            // BS
    float* cb    = ca + BS;           // BS
    float* wbuf  = cb + BS;           // BS
    float* scorp = wbuf + BS;         // 8*BS
    float* seqf  = scorp + 8 * BS;    // B*256
    float* wsumb = seqf + B * 256;    // B (pad 256)
    float* part  = wsumb + 256;       // B*16*256

    const int c0 = (3 * 256 * 256) / 4, c1 = (3 * 768 * 256) / 4,
              c2 = (3 * 768 * 256) / 4;
    const int cvtb = (c0 + c1 + c2 + 255) / 256;   // 1344
    cvt_embed_kernel<<<cvtb + BS / 64, 256, 0, stream>>>(
        attendW, attW_bf, c0, gruWih, wih_bf, c1, gruWhh, whh_bf, c2, cvtb,
        amino, embW, embB, neighW, neighB, alignW, hA, nb_bf, ca, cb);

    for (int d = 0; d < 3; ++d) {
        const ushort* h_in  = (d & 1) ? hB : hA;
        ushort*       h_out = (d & 1) ? hA : hB;
        if (d == 0) {
            gemm_dual_kernel<false><<<128 * 2, 256, 0, stream>>>(
                nb_bf, attW_bf, attendB, att_bf, 2, 256,
                (const float*)nullptr, (const float*)nullptr,
                (float*)nullptr, (float*)nullptr);
        } else {
            gemm_dual_kernel<true><<<128 * 2, 256, 0, stream>>>(
                h_in, attW_bf + d * 256 * 256, attendB + d * 256, att_bf, 2, 256,
                alignW + d * 512, alignW + d * 512 + 256, ca, cb);
        }
        attn_kernel<<<BS / 4, 256, 0, stream>>>(deg, ca, cb, att_bf, alignB, d, nb_bf, S);
        if (d < 2) {
            gru_fused_kernel<false><<<1024, 256, 0, stream>>>(
                nb_bf, wih_bf + d * 768 * 256, gruBih + d * 768,
                whh_bf + d * 768 * 256, gruBhh + d * 768, h_in, h_out,
                (const float*)nullptr, (float*)nullptr,
                (const float*)nullptr, (float*)nullptr, BS);
        } else {
            gru_fused_kernel<true><<<1024, 256, 0, stream>>>(
                nb_bf, wih_bf + d * 768 * 256, gruBih + d * 768,
                whh_bf + d * 768 * 256, gruBhh + d * 768, h_in, h_out,
                mask, part, saW + 256, scorp, BS);
        }
    }

    // final h = hB (d=2 writes hB); act = relu(hB)
    seqpool_sm_kernel<<<B, 256, 0, stream>>>(part, saW, scorp, saB, mask,
                                             seqf, wbuf, wsumb, 16, S, BS);
    sgru_tail_kernel<<<B, 256, 0, stream>>>(wbuf, hB, seqAttW, seqAttB, wsumb, seqf,
                                            sWih, sWhh, sBih, sBhh, out, S);
}

// Round 17
// 258.569 us; speedup vs baseline: 2.5033x; 2.5033x over previous
//
#include <hip/hip_runtime.h>
#include <hip/hip_bf16.h>
#include <math.h>

// ProGAT: B=32, S=512, K=21, F_in=26, E=256, R=3, T=2
// Round 17: REVERT round-16 tail mega-fusion (sgru_tail ran at 440+us / 1.5% occupancy:
// 512 serial global-latency iterations in a 32-block kernel -- same class of mistake as
// round 8). Tail restored to round-15 multi-launch form. Kept: cvt+embed merged launch.

#define NEGC (-9.0e8f)

typedef __attribute__((ext_vector_type(8))) short bf16x8;
typedef __attribute__((ext_vector_type(4))) float f32x4;

__device__ __forceinline__ ushort f2bf(float x) {
    union { float f; unsigned u; } v; v.f = x;
    unsigned r = v.u + 0x7FFF + ((v.u >> 16) & 1);
    return (ushort)(r >> 16);
}
__device__ __forceinline__ float bf2f(ushort u) {
    union { unsigned u; float f; } v; v.u = ((unsigned)u) << 16;
    return v.f;
}
__device__ __forceinline__ float sigm_fast(float x) {
    return 1.f / (1.f + __expf(-x));
}
__device__ __forceinline__ float tanh_fast(float x) {
    return 1.f - 2.f / (__expf(2.f * x) + 1.f);
}
__device__ __forceinline__ float elu_fast(float x) {
    return x > 0.f ? x : (__expf(x) - 1.f);
}
__device__ __forceinline__ bf16x8 relu_bf8(bf16x8 v) {
    bf16x8 r;
#pragma unroll
    for (int i = 0; i < 8; ++i)
        r[i] = (v[i] & (short)0x8000) ? (short)0 : v[i];
    return r;
}

typedef const __attribute__((address_space(1))) void gvoid_t;
typedef __attribute__((address_space(3))) void lvoid_t;

// ---------------- merged cvt (blocks 0..cvtb-1) + embed (rest) ----------------
__global__ __launch_bounds__(256) void cvt_embed_kernel(
    const float* __restrict__ s0, ushort* __restrict__ d0, int n0,
    const float* __restrict__ s1, ushort* __restrict__ d1, int n1,
    const float* __restrict__ s2, ushort* __restrict__ d2, int n2,
    int cvtb,
    const float* __restrict__ amino, const float* __restrict__ embW,
    const float* __restrict__ embB, const float* __restrict__ neighW,
    const float* __restrict__ neighB, const float* __restrict__ alignW,
    ushort* __restrict__ h_bf, ushort* __restrict__ nf_bf,
    float* __restrict__ ca, float* __restrict__ cb)
{
    if ((int)blockIdx.x < cvtb) {
        int i = blockIdx.x * 256 + threadIdx.x;
        const float* s; ushort* dst; int l;
        if (i < n0) { s = s0; dst = d0; l = i; }
        else if (i < n0 + n1) { s = s1; dst = d1; l = i - n0; }
        else if (i < n0 + n1 + n2) { s = s2; dst = d2; l = i - n0 - n1; }
        else return;
        float4 v = *reinterpret_cast<const float4*>(s + (size_t)l * 4);
        ushort4 o; o.x = f2bf(v.x); o.y = f2bf(v.y); o.z = f2bf(v.z); o.w = f2bf(v.w);
        *reinterpret_cast<ushort4*>(dst + (size_t)l * 4) = o;
        return;
    }
    const int FIN = 26, FPAD = 28, ROWS = 64;
    __shared__ __align__(16) float xs[ROWS][FPAD];
    __shared__ float red1[ROWS][4];
    __shared__ float red2[ROWS][4];
    int tid = threadIdx.x;
    int lane = tid & 63, wv = tid >> 6;
    float wE[FPAD], wN[FPAD];
#pragma unroll
    for (int f = 0; f < FIN; ++f) {
        wE[f] = embW[tid * FIN + f];
        wN[f] = neighW[tid * FIN + f];
    }
    wE[26] = wE[27] = wN[26] = wN[27] = 0.f;
    float b1 = embB[tid], b2 = neighB[tid];
    float w1t = alignW[tid], w2t = alignW[256 + tid];
    int row0 = (blockIdx.x - cvtb) * ROWS;
    for (int idx = tid; idx < ROWS * FPAD; idx += 256) {
        int r = idx / FPAD, f = idx - r * FPAD;
        xs[r][f] = (f < FIN) ? amino[(size_t)(row0 + r) * FIN + f] : 0.f;
    }
    __syncthreads();
    for (int r = 0; r < ROWS; ++r) {
        const float4* x4 = reinterpret_cast<const float4*>(xs[r]);
        float a = b1, c = b2;
#pragma unroll
        for (int q = 0; q < 7; ++q) {
            float4 x = x4[q];
            a = fmaf(x.x, wE[4 * q], a);     c = fmaf(x.x, wN[4 * q], c);
            a = fmaf(x.y, wE[4 * q + 1], a); c = fmaf(x.y, wN[4 * q + 1], c);
            a = fmaf(x.z, wE[4 * q + 2], a); c = fmaf(x.z, wN[4 * q + 2], c);
            a = fmaf(x.w, wE[4 * q + 3], a); c = fmaf(x.w, wN[4 * q + 3], c);
        }
        a = a > 0.f ? a : 0.01f * a;
        c = c > 0.f ? c : 0.01f * c;
        size_t idx = (size_t)(row0 + r) * 256 + tid;
        h_bf[idx] = f2bf(a);
        nf_bf[idx] = f2bf(c);
        float p1 = a * w1t, p2 = c * w2t;
#pragma unroll
        for (int off = 32; off > 0; off >>= 1) {
            p1 += __shfl_down(p1, off);
            p2 += __shfl_down(p2, off);
        }
        if (lane == 0) { red1[r][wv] = p1; red2[r][wv] = p2; }
    }
    __syncthreads();
    if (tid < ROWS)
        ca[row0 + tid] = red1[tid][0] + red1[tid][1] + red1[tid][2] + red1[tid][3];
    else if (tid < 2 * ROWS) {
        int r = tid - ROWS;
        cb[row0 + r] = red2[r][0] + red2[r][1] + red2[r][2] + red2[r][3];
    }
}

// ---------------- bf16 MFMA GEMM (attend) + optional per-row dots over A0 ----------
template<bool RELUA>
__global__ __launch_bounds__(256) void gemm_dual_kernel(
    const ushort* __restrict__ A0, const ushort* __restrict__ W0,
    const float* __restrict__ b0, ushort* __restrict__ C0, int n0t,
    int K,
    const float* __restrict__ dw1, const float* __restrict__ dw2,
    float* __restrict__ dout1, float* __restrict__ dout2)
{
    __shared__ __align__(16) short As[128 * 32];
    __shared__ __align__(16) short Bs[128 * 32];
    int nwg = gridDim.x;
    int q = nwg >> 3;
    int flat = blockIdx.x;
    int sw = (flat & 7) * q + (flat >> 3);
    int bmi = sw / n0t, bni = sw - bmi * n0t;
    const ushort* A = A0; const ushort* W = W0; const float* bias = b0;
    ushort* C = C0; int N = n0t << 7; int bn = bni << 7;
    int bm = bmi << 7;

    int tid = threadIdx.x;
    int lane = tid & 63;
    int w = tid >> 6;
    int wr = w >> 1, wc = w & 1;
    bool dots = (dout1 != nullptr) && (bni == 0);

    f32x4 acc[4][4];
#pragma unroll
    for (int m = 0; m < 4; ++m)
#pragma unroll
        for (int n = 0; n < 4; ++n) acc[m][n] = (f32x4){0.f, 0.f, 0.f, 0.f};
    float p1 = 0.f, p2 = 0.f;

    for (int k0 = 0; k0 < K; k0 += 32) {
#pragma unroll
        for (int i = 0; i < 2; ++i) {
            int e = w * 1024 + i * 512 + lane * 8;
            int r = e >> 5, c = e & 31;
            const ushort* ga = A + (size_t)(bm + r) * K + (k0 + c);
            const ushort* gw = W + (size_t)(bn + r) * K + (k0 + c);
            __builtin_amdgcn_global_load_lds((gvoid_t*)ga, (lvoid_t*)&As[w * 1024 + i * 512], 16, 0, 0);
            __builtin_amdgcn_global_load_lds((gvoid_t*)gw, (lvoid_t*)&Bs[w * 1024 + i * 512], 16, 0, 0);
        }
        __syncthreads();
        bf16x8 af[4], bw[4];
        int ra = wr * 64 + (lane & 15);
        int rb = wc * 64 + (lane & 15);
        int kc = (lane >> 4) * 8;
#pragma unroll
        for (int m = 0; m < 4; ++m) {
            af[m] = *reinterpret_cast<const bf16x8*>(&As[(ra + m * 16) * 32 + kc]);
            if (RELUA) af[m] = relu_bf8(af[m]);
        }
#pragma unroll
        for (int n = 0; n < 4; ++n)
            bw[n] = *reinterpret_cast<const bf16x8*>(&Bs[(rb + n * 16) * 32 + kc]);
#pragma unroll
        for (int m = 0; m < 4; ++m)
#pragma unroll
            for (int n = 0; n < 4; ++n)
                acc[m][n] = __builtin_amdgcn_mfma_f32_16x16x32_bf16(af[m], bw[n], acc[m][n], 0, 0, 0);
        if (dots) {
            int drow = tid >> 1, kh = (tid & 1) << 4;
            const short* ar = &As[drow * 32 + kh];
#pragma unroll
            for (int c = 0; c < 16; ++c) {
                float av = bf2f((ushort)ar[c]);
                if (RELUA) av = fmaxf(av, 0.f);
                p1 = fmaf(av, dw1[k0 + kh + c], p1);
                p2 = fmaf(av, dw2[k0 + kh + c], p2);
            }
        }
        __syncthreads();
    }

    if (dots) {
        p1 += __shfl_xor(p1, 1);
        p2 += __shfl_xor(p2, 1);
        if ((tid & 1) == 0) {
            dout1[bm + (tid >> 1)] = p1;
            dout2[bm + (tid >> 1)] = p2;
        }
    }

    int cr0 = bm + wr * 64 + ((lane >> 4) * 4);
    int cc0 = bn + wc * 64 + (lane & 15);
#pragma unroll
    for (int n = 0; n < 4; ++n) {
        int col = cc0 + n * 16;
        float bv = bias[col];
#pragma unroll
        for (int m = 0; m < 4; ++m) {
            int row0 = cr0 + m * 16;
#pragma unroll
            for (int j = 0; j < 4; ++j) {
                float v = acc[m][n][j] + bv;
                C[(size_t)(row0 + j) * N + col] = f2bf(v);
            }
        }
    }
}

// ---------------- fused GRU GEMM+gate v2 (64x64 tile, double-buffered h) ------------
template<bool TAIL>
__global__ __launch_bounds__(256) void gru_fused_kernel(
    const ushort* __restrict__ ctx, const ushort* __restrict__ wih,
    const float* __restrict__ bih, const ushort* __restrict__ whh,
    const float* __restrict__ bhh,
    const ushort* __restrict__ h_in, ushort* __restrict__ h_out,
    const float* __restrict__ mask, float* __restrict__ pool_part,
    const float* __restrict__ dsw, float* __restrict__ scor_part, int BS)
{
    __shared__ __align__(16) short lds[16384];   // 8 panels x [64][32]
    int flat = blockIdx.x;                       // 1024
    int sw = (flat & 7) * 128 + (flat >> 3);     // bijective XCD swizzle
    int bmi = sw >> 2, ct = sw & 3;
    int bm = bmi << 6;
    int tid = threadIdx.x;
    int lane = tid & 63;
    int w = tid >> 6;
    int wr = w >> 1, wc = w & 1;

    f32x4 acc[6][2][2];
#pragma unroll
    for (int qq = 0; qq < 6; ++qq)
#pragma unroll
        for (int m = 0; m < 2; ++m)
#pragma unroll
            for (int n = 0; n < 2; ++n) acc[qq][m][n] = (f32x4){0.f, 0.f, 0.f, 0.f};

    int srow = tid >> 2, scol = (tid & 3) << 3;
    int ldst = (tid & 0xC0) * 8;
    for (int k0 = 0; k0 < 256; k0 += 32) {
        {
            const ushort* s0 = ctx  + (size_t)(bm + srow) * 256 + k0 + scol;
            const ushort* s1 = h_in + (size_t)(bm + srow) * 256 + k0 + scol;
            __builtin_amdgcn_global_load_lds((gvoid_t*)s0, (lvoid_t*)&lds[ldst], 16, 0, 0);
            __builtin_amdgcn_global_load_lds((gvoid_t*)s1, (lvoid_t*)&lds[2048 + ldst], 16, 0, 0);
#pragma unroll
            for (int qq = 0; qq < 6; ++qq) {
                const ushort* wb = (qq < 3) ? wih : whh;
                int slice = (qq < 3) ? qq : qq - 3;
                const ushort* sv = wb + (size_t)(slice * 256 + ct * 64 + srow) * 256 + k0 + scol;
                __builtin_amdgcn_global_load_lds((gvoid_t*)sv,
                    (lvoid_t*)&lds[(2 + qq) * 2048 + ldst], 16, 0, 0);
            }
        }
        __syncthreads();
        int rl = lane & 15;
        int kc = (lane >> 4) * 8;
        bf16x8 a_c[2], a_h[2];
#pragma unroll
        for (int m = 0; m < 2; ++m) {
            a_c[m] = *reinterpret_cast<const bf16x8*>(&lds[(wr * 32 + m * 16 + rl) * 32 + kc]);
            a_h[m] = *reinterpret_cast<const bf16x8*>(&lds[2048 + (wr * 32 + m * 16 + rl) * 32 + kc]);
        }
#pragma unroll
        for (int qq = 0; qq < 6; ++qq) {
            bf16x8 bw[2];
#pragma unroll
            for (int n = 0; n < 2; ++n)
                bw[n] = *reinterpret_cast<const bf16x8*>(
                    &lds[(2 + qq) * 2048 + (wc * 32 + n * 16 + rl) * 32 + kc]);
#pragma unroll
            for (int m = 0; m < 2; ++m)
#pragma unroll
                for (int n = 0; n < 2; ++n)
                    acc[qq][m][n] = __builtin_amdgcn_mfma_f32_16x16x32_bf16(
                        (qq < 3) ? a_c[m] : a_h[m], bw[n], acc[qq][m][n], 0, 0, 0);
        }
        __syncthreads();
    }

    int rl = lane & 15;
    int r0 = (lane >> 4) * 4;
    float mv[2][4];
    float dswv[2];
    if (TAIL) {
        int b_ = bm >> 9;
        int sbase = bm & 511;
#pragma unroll
        for (int m = 0; m < 2; ++m)
#pragma unroll
            for (int j = 0; j < 4; ++j)
                mv[m][j] = mask[b_ * 512 + sbase + wr * 32 + m * 16 + r0 + j];
#pragma unroll
        for (int n = 0; n < 2; ++n)
            dswv[n] = dsw[ct * 64 + wc * 32 + n * 16 + rl];
    }
    float pm[2] = {0.f, 0.f};
    float ps[2][4] = {{0.f, 0.f, 0.f, 0.f}, {0.f, 0.f, 0.f, 0.f}};

#pragma unroll
    for (int n = 0; n < 2; ++n) {
        int col = ct * 64 + wc * 32 + n * 16 + rl;
        float bir = bih[col], biz = bih[256 + col], bin = bih[512 + col];
        float bhr = bhh[col], bhz = bhh[256 + col], bhn = bhh[512 + col];
#pragma unroll
        for (int m = 0; m < 2; ++m) {
            int row0 = bm + wr * 32 + m * 16 + r0;
#pragma unroll
            for (int j = 0; j < 4; ++j) {
                size_t idx = (size_t)(row0 + j) * 256 + col;
                float r = sigm_fast(acc[0][m][n][j] + bir + acc[3][m][n][j] + bhr);
                float z = sigm_fast(acc[1][m][n][j] + biz + acc[4][m][n][j] + bhz);
                float nn = tanh_fast(acc[2][m][n][j] + bin + r * (acc[5][m][n][j] + bhn));
                float hold = bf2f(h_in[idx]);
                float hh = (1.f - z) * nn + z * hold;
                ushort hb = f2bf(hh);
                h_out[idx] = hb;
                if (TAIL) {
                    float a = fmaxf(bf2f(hb), 0.f);
                    pm[n] = fmaf(a, mv[m][j], pm[n]);
                    ps[m][j] = fmaf(a, dswv[n], ps[m][j]);
                }
            }
        }
    }

    if (TAIL) {
#pragma unroll
        for (int n = 0; n < 2; ++n) {
            float p = pm[n];
            p += __shfl_xor(p, 16);
            p += __shfl_xor(p, 32);
            if (lane < 16) {
                int b_ = bm >> 9;
                int sc = ((bm & 511) >> 5) + wr;
                int col = ct * 64 + wc * 32 + n * 16 + rl;
                pool_part[((size_t)b_ * 16 + sc) * 256 + col] = p;
            }
        }
#pragma unroll
        for (int m = 0; m < 2; ++m)
#pragma unroll
            for (int j = 0; j < 4; ++j) {
                float p = ps[m][j];
                p += __shfl_xor(p, 1);
                p += __shfl_xor(p, 2);
                p += __shfl_xor(p, 4);
                p += __shfl_xor(p, 8);
                if (rl == 0) {
                    int row = bm + wr * 32 + m * 16 + r0 + j;
                    scor_part[(size_t)(ct * 2 + wc) * BS + row] = p;
                }
            }
    }
}

// attn: 4 rows/block, one wave per row, BRANCHLESS bf16 gather
__global__ __launch_bounds__(256) void attn_kernel(
    const int* __restrict__ deg, const float* __restrict__ ca,
    const float* __restrict__ cbrow, const ushort* __restrict__ act_t,
    const float* __restrict__ alignB, int d,
    ushort* __restrict__ context_bf, int S)
{
    const int KNB = 21;
    int raw = blockIdx.x;
    int bid = (raw & 7) * 512 + (raw >> 3);
    int bs0 = bid * 4;
    int b = bs0 >> 9;
    int tid = threadIdx.x;
    int wv = tid >> 6, lane = tid & 63;
    int bs = bs0 + wv;
    __shared__ float ss[4][KNB];
    __shared__ int   sj[4][KNB];
    if (lane < KNB) {
        int j = deg[bs * KNB + lane];
        float cbv = (j >= 0) ? cbrow[b * S + j] : 0.f;
        float sc = ca[bs] + cbv + alignB[d];
        sc = sc > 0.f ? sc : 0.01f * sc;
        if (j < 0) sc += NEGC;
        sj[wv][lane] = j;
        ss[wv][lane] = sc;
    }
    __syncthreads();
    float mx = -3.4e38f;
#pragma unroll
    for (int k = 0; k < KNB; ++k) mx = fmaxf(mx, ss[wv][k]);
    float se[KNB];
    int js[KNB];
    float sum = 0.f;
#pragma unroll
    for (int k = 0; k < KNB; ++k) {
        int j = sj[wv][k];
        float e = __expf(ss[wv][k] - mx);
        sum += e;
        se[k] = (j >= 0) ? e : 0.f;
        js[k] = (j >= 0) ? j : 0;
    }
    float inv = 1.f / sum;
    const ushort* base = act_t + (size_t)b * S * 256 + lane * 4;
    float a0 = 0.f, a1 = 0.f, a2 = 0.f, a3 = 0.f;
#pragma unroll
    for (int k = 0; k < KNB; ++k) {
        ushort4 v = *reinterpret_cast<const ushort4*>(base + (size_t)js[k] * 256);
        float wk = se[k];
        a0 = fmaf(wk, bf2f(v.x), a0);
        a1 = fmaf(wk, bf2f(v.y), a1);
        a2 = fmaf(wk, bf2f(v.z), a2);
        a3 = fmaf(wk, bf2f(v.w), a3);
    }
    ushort4 o;
    o.x = f2bf(elu_fast(a0 * inv));
    o.y = f2bf(elu_fast(a1 * inv));
    o.z = f2bf(elu_fast(a2 * inv));
    o.w = f2bf(elu_fast(a3 * inv));
    *reinterpret_cast<ushort4*>(&context_bf[(size_t)bs * 256 + lane * 4]) = o;
}

// fused: combine pool partials -> seqfeat + moldot; praw from scor_part (8 slices);
// softmax over S -> wbuf; masked weight sum -> wsumb.
__global__ __launch_bounds__(256) void seqpool_sm_kernel(
    const float* __restrict__ partial, const float* __restrict__ saW,
    const float* __restrict__ scor_part, const float* __restrict__ sab,
    const float* __restrict__ mask,
    float* __restrict__ seqfeat, float* __restrict__ wout,
    float* __restrict__ wsumb, int NC, int S, int BS)
{
    int b = blockIdx.x, tid = threadIdx.x;
    int lane = tid & 63, wv = tid >> 6;
    __shared__ float red[4];
    __shared__ float sw[512];
    __shared__ float r1[4], r2[4], r3[4];
    __shared__ float smd;
    float acc = 0.f;
    for (int c = 0; c < NC; ++c)
        acc += partial[((size_t)b * NC + c) * 256 + tid];
    seqfeat[b * 256 + tid] = acc;
    float am = fmaxf(acc, 0.f);
    float p = am * saW[tid];
#pragma unroll
    for (int off = 32; off > 0; off >>= 1) p += __shfl_down(p, off);
    if (lane == 0) red[wv] = p;
    __syncthreads();
    if (tid == 0) smd = red[0] + red[1] + red[2] + red[3];
    __syncthreads();
    float md = smd, sb = sab[0];
    float lm = -3.4e38f;
    for (int s = tid; s < S; s += 256) {
        int row = b * S + s;
        float praw = 0.f;
#pragma unroll
        for (int sl = 0; sl < 8; ++sl) praw += scor_part[(size_t)sl * BS + row];
        float sc = md + praw + sb;
        sc = sc > 0.f ? sc : 0.01f * sc;
        if (mask[row] == 0.f) sc += NEGC;
        sw[s] = sc;
        lm = fmaxf(lm, sc);
    }
#pragma unroll
    for (int off = 32; off > 0; off >>= 1) lm = fmaxf(lm, __shfl_down(lm, off));
    if (lane == 0) r1[wv] = lm;
    __syncthreads();
    float mx = fmaxf(fmaxf(r1[0], r1[1]), fmaxf(r1[2], r1[3]));
    float ls = 0.f, ms = 0.f;
    for (int s = tid; s < S; s += 256) {
        float e = __expf(sw[s] - mx);
        float em = e * mask[b * S + s];
        sw[s] = em;
        ls += e;
        ms += em;
    }
#pragma unroll
    for (int off = 32; off > 0; off >>= 1) {
        ls += __shfl_down(ls, off);
        ms += __shfl_down(ms, off);
    }
    if (lane == 0) { r2[wv] = ls; r3[wv] = ms; }
    __syncthreads();
    float inv = 1.f / (r2[0] + r2[1] + r2[2] + r2[3]);
    if (tid == 0) wsumb[b] = (r3[0] + r3[1] + r3[2] + r3[3]) * inv;
    for (int s = tid; s < S; s += 256)
        wout[b * S + s] = sw[s] * inv;
}

// weighted act pool partials (act = relu(h))
__global__ __launch_bounds__(256) void wpool_kernel(
    const float* __restrict__ w, const ushort* __restrict__ h,
    float* __restrict__ vpart, int S, int CH)
{
    int bc = blockIdx.x;
    int NC = S / CH;
    int b = bc / NC, c = bc - b * NC;
    int tid = threadIdx.x;
    int s0 = c * CH;
    const ushort* ab = h + ((size_t)b * S + s0) * 256;
    const float* wb = w + b * S + s0;
    float acc = 0.f;
    for (int s = 0; s < CH; ++s)
        acc = fmaf(wb[s], fmaxf(bf2f(ab[(size_t)s * 256 + tid]), 0.f), acc);
    vpart[(size_t)bc * 256 + tid] = acc;
}

// sctx[b,col] = elu( (sum_c vpart[b,c,:]) . seqAttW[col,:] + wsumb[b]*seqAttB[col] )
__global__ __launch_bounds__(256) void sctx_mm_kernel(
    const float* __restrict__ vpart, const float* __restrict__ seqAttW,
    const float* __restrict__ seqAttB, const float* __restrict__ wsumb,
    float* __restrict__ sctx, int NC)
{
    int o = blockIdx.x * 4 + (threadIdx.x >> 6);
    int lane = threadIdx.x & 63;
    int b = o >> 8, col = o & 255;
    const float* wr_ = seqAttW + (size_t)col * 256;
    float p = 0.f;
#pragma unroll
    for (int i = 0; i < 4; ++i) {
        int idx = lane + 64 * i;
        float v = 0.f;
        for (int c = 0; c < 16; ++c)
            v += vpart[((size_t)b * 16 + c) * 256 + idx];
        p = fmaf(v, wr_[idx], p);
    }
#pragma unroll
    for (int off = 32; off > 0; off >>= 1) p += __shfl_down(p, off);
    if (lane == 0)
        sctx[o] = elu_fast(p + wsumb[b] * seqAttB[col]);
}

// sgru matmuls. full=1: both halves; full=0: only gh (gi reused from t=0)
__global__ __launch_bounds__(256) void sgru_mm_kernel(
    const float* __restrict__ x, const float* __restrict__ hseq,
    const float* __restrict__ wih, const float* __restrict__ whh,
    const float* __restrict__ bih, const float* __restrict__ bhh,
    float* __restrict__ g, int full)
{
    int per_b = full ? 1536 : 768;
    int o = blockIdx.x * 4 + (threadIdx.x >> 6);
    int lane = threadIdx.x & 63;
    int b = o / per_b;
    int j = o - b * per_b;
    if (!full) j += 768;
    const float* src; const float* w; const float* bp; int jj;
    if (j < 768) { src = x + b * 256; w = wih; bp = bih; jj = j; }
    else         { src = hseq + b * 256; w = whh; bp = bhh; jj = j - 768; }
    float p = 0.f;
#pragma unroll
    for (int i = 0; i < 4; ++i) {
        int idx = lane + 64 * i;
        p = fmaf(src[idx], w[(size_t)jj * 256 + idx], p);
    }
#pragma unroll
    for (int off = 32; off > 0; off >>= 1) p += __shfl_down(p, off);
    if (lane == 0) g[b * 1536 + j] = p + bp[jj];
}

__global__ __launch_bounds__(256) void sgru_gate_kernel(
    const float* __restrict__ g, float* __restrict__ hseq, float* __restrict__ out)
{
    int b = blockIdx.x, e = threadIdx.x;
    const float* gr = g + b * 1536;
    float r = sigm_fast(gr[e] + gr[768 + e]);
    float z = sigm_fast(gr[256 + e] + gr[1024 + e]);
    float n = tanh_fast(gr[512 + e] + r * gr[1280 + e]);
    float hv = hseq[b * 256 + e];
    float hn = (1.f - z) * n + z * hv;
    hseq[b * 256 + e] = hn;
    out[b * 256 + e] = fmaxf(hn, 0.f);
}

extern "C" void kernel_launch(void* const* d_in, const int* in_sizes, int n_in,
                              void* d_out, int out_size, void* d_ws, size_t ws_size,
                              hipStream_t stream)
{
    const float* amino   = (const float*)d_in[0];
    const int*   deg     = (const int*)  d_in[1];
    const float* mask    = (const float*)d_in[2];
    const float* embW    = (const float*)d_in[3];
    const float* embB    = (const float*)d_in[4];
    const float* neighW  = (const float*)d_in[5];
    const float* neighB  = (const float*)d_in[6];
    const float* alignW  = (const float*)d_in[7];
    const float* alignB  = (const float*)d_in[8];
    const float* attendW = (const float*)d_in[9];
    const float* attendB = (const float*)d_in[10];
    const float* gruWih  = (const float*)d_in[11];
    const float* gruWhh  = (const float*)d_in[12];
    const float* gruBih  = (const float*)d_in[13];
    const float* gruBhh  = (const float*)d_in[14];
    const float* saW     = (const float*)d_in[15];
    const float* saB     = (const float*)d_in[16];
    const float* seqAttW = (const float*)d_in[17];
    const float* seqAttB = (const float*)d_in[18];
    const float* sWih    = (const float*)d_in[19];
    const float* sWhh    = (const float*)d_in[20];
    const float* sBih    = (const float*)d_in[21];
    const float* sBhh    = (const float*)d_in[22];
    float* out = (float*)d_out;

    const int B = 32, S = 512;
    const int BS = B * S;                 // 16384
    const size_t N1 = (size_t)BS * 256;   // 4194304

    ushort* hA     = (ushort*)d_ws;              // N1 (bf16 GRU state, ping)
    ushort* hB     = hA + N1;                    // N1 (pong)
    ushort* nb_bf  = hB + N1;                    // N1 (nf round 0, then context)
    ushort* att_bf = nb_bf + N1;                 // N1 (act_t)
    ushort* attW_bf = att_bf + N1;               // 3*256*256
    ushort* wih_bf  = attW_bf + 3 * 256 * 256;   // 3*768*256
    ushort* whh_bf  = wih_bf + 3 * 768 * 256;
    float* smalls = (float*)(whh_bf + 3 * 768 * 256);
    float* ca    = smalls;            // BS
    float* cb    = ca + BS;           // BS
    float* wbuf  = cb + BS;           // BS
    float* scorp = wbuf + BS;         // 8*BS
    float* seqf  = scorp + 8 * BS;    // B*256
    float* sctx  = seqf + B * 256;    // B*256
    float* wsumb = sctx + B * 256;    // B (pad 256)
    float* g     = wsumb + 256;       // B*1536
    float* part  = g + B * 1536;      // B*16*256
    float* vpart = part + B * 16 * 256; // B*16*256

    const int c0 = (3 * 256 * 256) / 4, c1 = (3 * 768 * 256) / 4,
              c2 = (3 * 768 * 256) / 4;
    const int cvtb = (c0 + c1 + c2 + 255) / 256;
    cvt_embed_kernel<<<cvtb + BS / 64, 256, 0, stream>>>(
        attendW, attW_bf, c0, gruWih, wih_bf, c1, gruWhh, whh_bf, c2, cvtb,
        amino, embW, embB, neighW, neighB, alignW, hA, nb_bf, ca, cb);

    for (int d = 0; d < 3; ++d) {
        const ushort* h_in  = (d & 1) ? hB : hA;
        ushort*       h_out = (d & 1) ? hA : hB;
        if (d == 0) {
            gemm_dual_kernel<false><<<128 * 2, 256, 0, stream>>>(
                nb_bf, attW_bf, attendB, att_bf, 2, 256,
                (const float*)nullptr, (const float*)nullptr,
                (float*)nullptr, (float*)nullptr);
        } else {
            gemm_dual_kernel<true><<<128 * 2, 256, 0, stream>>>(
                h_in, attW_bf + d * 256 * 256, attendB + d * 256, att_bf, 2, 256,
                alignW + d * 512, alignW + d * 512 + 256, ca, cb);
        }
        attn_kernel<<<BS / 4, 256, 0, stream>>>(deg, ca, cb, att_bf, alignB, d, nb_bf, S);
        if (d < 2) {
            gru_fused_kernel<false><<<1024, 256, 0, stream>>>(
                nb_bf, wih_bf + d * 768 * 256, gruBih + d * 768,
                whh_bf + d * 768 * 256, gruBhh + d * 768, h_in, h_out,
                (const float*)nullptr, (float*)nullptr,
                (const float*)nullptr, (float*)nullptr, BS);
        } else {
            gru_fused_kernel<true><<<1024, 256, 0, stream>>>(
                nb_bf, wih_bf + d * 768 * 256, gruBih + d * 768,
                whh_bf + d * 768 * 256, gruBhh + d * 768, h_in, h_out,
                mask, part, saW + 256, scorp, BS);
        }
    }

    // final h = hB (d=2 writes hB); act = relu(hB)
    seqpool_sm_kernel<<<B, 256, 0, stream>>>(part, saW, scorp, saB, mask,
                                             seqf, wbuf, wsumb, 16, S, BS);
    wpool_kernel<<<B * 16, 256, 0, stream>>>(wbuf, hB, vpart, S, 32);
    sctx_mm_kernel<<<B * 256 / 4, 256, 0, stream>>>(vpart, seqAttW, seqAttB, wsumb, sctx, 16);

    sgru_mm_kernel<<<B * 1536 / 4, 256, 0, stream>>>(sctx, seqf, sWih, sWhh, sBih, sBhh, g, 1);
    sgru_gate_kernel<<<B, 256, 0, stream>>>(g, seqf, out);
    sgru_mm_kernel<<<B * 768 / 4, 256, 0, stream>>>(sctx, seqf, sWih, sWhh, sBih, sBhh, g, 0);
    sgru_gate_kernel<<<B, 256, 0, stream>>>(g, seqf, out);
}

// Round 18
// 245.578 us; speedup vs baseline: 2.6357x; 1.0529x over previous
//
#include <hip/hip_runtime.h>
#include <hip/hip_bf16.h>
#include <math.h>

// ProGAT: B=32, S=512, K=21, F_in=26, E=256, R=3, T=2
// Round 18: revert cvt+embed merge (merged kernel spilled wE/wN arrays to scratch:
// VGPR=48 < 56 needed, 63us vs ~10us separate). Exact round-15 structure (session
// best 245.9us): separate cvt3 + embed; branchless attn; 64x64 gru_fused template<TAIL>;
// act recomputed as relu(h); tail = seqpool_sm + wpool + sctx_mm + sgru chain.

#define NEGC (-9.0e8f)

typedef __attribute__((ext_vector_type(8))) short bf16x8;
typedef __attribute__((ext_vector_type(4))) float f32x4;

__device__ __forceinline__ ushort f2bf(float x) {
    union { float f; unsigned u; } v; v.f = x;
    unsigned r = v.u + 0x7FFF + ((v.u >> 16) & 1);
    return (ushort)(r >> 16);
}
__device__ __forceinline__ float bf2f(ushort u) {
    union { unsigned u; float f; } v; v.u = ((unsigned)u) << 16;
    return v.f;
}
__device__ __forceinline__ float sigm_fast(float x) {
    return 1.f / (1.f + __expf(-x));
}
__device__ __forceinline__ float tanh_fast(float x) {
    return 1.f - 2.f / (__expf(2.f * x) + 1.f);
}
__device__ __forceinline__ float elu_fast(float x) {
    return x > 0.f ? x : (__expf(x) - 1.f);
}
__device__ __forceinline__ bf16x8 relu_bf8(bf16x8 v) {
    bf16x8 r;
#pragma unroll
    for (int i = 0; i < 8; ++i)
        r[i] = (v[i] & (short)0x8000) ? (short)0 : v[i];
    return r;
}

typedef const __attribute__((address_space(1))) void gvoid_t;
typedef __attribute__((address_space(3))) void lvoid_t;

__global__ __launch_bounds__(256) void cvt3_kernel(
    const float* __restrict__ s0, ushort* __restrict__ d0, int n0,
    const float* __restrict__ s1, ushort* __restrict__ d1, int n1,
    const float* __restrict__ s2, ushort* __restrict__ d2, int n2)
{
    int i = blockIdx.x * 256 + threadIdx.x;
    const float* s; ushort* dst; int l;
    if (i < n0) { s = s0; dst = d0; l = i; }
    else if (i < n0 + n1) { s = s1; dst = d1; l = i - n0; }
    else if (i < n0 + n1 + n2) { s = s2; dst = d2; l = i - n0 - n1; }
    else return;
    float4 v = *reinterpret_cast<const float4*>(s + (size_t)l * 4);
    ushort4 o; o.x = f2bf(v.x); o.y = f2bf(v.y); o.z = f2bf(v.z); o.w = f2bf(v.w);
    *reinterpret_cast<ushort4*>(dst + (size_t)l * 4) = o;
}

// ---------------- bf16 MFMA GEMM (attend) + optional per-row dots over A0 ----------
template<bool RELUA>
__global__ __launch_bounds__(256) void gemm_dual_kernel(
    const ushort* __restrict__ A0, const ushort* __restrict__ W0,
    const float* __restrict__ b0, ushort* __restrict__ C0, int n0t,
    int K,
    const float* __restrict__ dw1, const float* __restrict__ dw2,
    float* __restrict__ dout1, float* __restrict__ dout2)
{
    __shared__ __align__(16) short As[128 * 32];
    __shared__ __align__(16) short Bs[128 * 32];
    int nwg = gridDim.x;
    int q = nwg >> 3;
    int flat = blockIdx.x;
    int sw = (flat & 7) * q + (flat >> 3);
    int bmi = sw / n0t, bni = sw - bmi * n0t;
    const ushort* A = A0; const ushort* W = W0; const float* bias = b0;
    ushort* C = C0; int N = n0t << 7; int bn = bni << 7;
    int bm = bmi << 7;

    int tid = threadIdx.x;
    int lane = tid & 63;
    int w = tid >> 6;
    int wr = w >> 1, wc = w & 1;
    bool dots = (dout1 != nullptr) && (bni == 0);

    f32x4 acc[4][4];
#pragma unroll
    for (int m = 0; m < 4; ++m)
#pragma unroll
        for (int n = 0; n < 4; ++n) acc[m][n] = (f32x4){0.f, 0.f, 0.f, 0.f};
    float p1 = 0.f, p2 = 0.f;

    for (int k0 = 0; k0 < K; k0 += 32) {
#pragma unroll
        for (int i = 0; i < 2; ++i) {
            int e = w * 1024 + i * 512 + lane * 8;
            int r = e >> 5, c = e & 31;
            const ushort* ga = A + (size_t)(bm + r) * K + (k0 + c);
            const ushort* gw = W + (size_t)(bn + r) * K + (k0 + c);
            __builtin_amdgcn_global_load_lds((gvoid_t*)ga, (lvoid_t*)&As[w * 1024 + i * 512], 16, 0, 0);
            __builtin_amdgcn_global_load_lds((gvoid_t*)gw, (lvoid_t*)&Bs[w * 1024 + i * 512], 16, 0, 0);
        }
        __syncthreads();
        bf16x8 af[4], bw[4];
        int ra = wr * 64 + (lane & 15);
        int rb = wc * 64 + (lane & 15);
        int kc = (lane >> 4) * 8;
#pragma unroll
        for (int m = 0; m < 4; ++m) {
            af[m] = *reinterpret_cast<const bf16x8*>(&As[(ra + m * 16) * 32 + kc]);
            if (RELUA) af[m] = relu_bf8(af[m]);
        }
#pragma unroll
        for (int n = 0; n < 4; ++n)
            bw[n] = *reinterpret_cast<const bf16x8*>(&Bs[(rb + n * 16) * 32 + kc]);
#pragma unroll
        for (int m = 0; m < 4; ++m)
#pragma unroll
            for (int n = 0; n < 4; ++n)
                acc[m][n] = __builtin_amdgcn_mfma_f32_16x16x32_bf16(af[m], bw[n], acc[m][n], 0, 0, 0);
        if (dots) {
            int drow = tid >> 1, kh = (tid & 1) << 4;
            const short* ar = &As[drow * 32 + kh];
#pragma unroll
            for (int c = 0; c < 16; ++c) {
                float av = bf2f((ushort)ar[c]);
                if (RELUA) av = fmaxf(av, 0.f);
                p1 = fmaf(av, dw1[k0 + kh + c], p1);
                p2 = fmaf(av, dw2[k0 + kh + c], p2);
            }
        }
        __syncthreads();
    }

    if (dots) {
        p1 += __shfl_xor(p1, 1);
        p2 += __shfl_xor(p2, 1);
        if ((tid & 1) == 0) {
            dout1[bm + (tid >> 1)] = p1;
            dout2[bm + (tid >> 1)] = p2;
        }
    }

    int cr0 = bm + wr * 64 + ((lane >> 4) * 4);
    int cc0 = bn + wc * 64 + (lane & 15);
#pragma unroll
    for (int n = 0; n < 4; ++n) {
        int col = cc0 + n * 16;
        float bv = bias[col];
#pragma unroll
        for (int m = 0; m < 4; ++m) {
            int row0 = cr0 + m * 16;
#pragma unroll
            for (int j = 0; j < 4; ++j) {
                float v = acc[m][n][j] + bv;
                C[(size_t)(row0 + j) * N + col] = f2bf(v);
            }
        }
    }
}

// ---------------- fused GRU GEMM+gate v2 (64x64 tile, double-buffered h) ------------
template<bool TAIL>
__global__ __launch_bounds__(256) void gru_fused_kernel(
    const ushort* __restrict__ ctx, const ushort* __restrict__ wih,
    const float* __restrict__ bih, const ushort* __restrict__ whh,
    const float* __restrict__ bhh,
    const ushort* __restrict__ h_in, ushort* __restrict__ h_out,
    const float* __restrict__ mask, float* __restrict__ pool_part,
    const float* __restrict__ dsw, float* __restrict__ scor_part, int BS)
{
    __shared__ __align__(16) short lds[16384];   // 8 panels x [64][32]
    int flat = blockIdx.x;                       // 1024
    int sw = (flat & 7) * 128 + (flat >> 3);     // bijective XCD swizzle
    int bmi = sw >> 2, ct = sw & 3;
    int bm = bmi << 6;
    int tid = threadIdx.x;
    int lane = tid & 63;
    int w = tid >> 6;
    int wr = w >> 1, wc = w & 1;

    f32x4 acc[6][2][2];
#pragma unroll
    for (int qq = 0; qq < 6; ++qq)
#pragma unroll
        for (int m = 0; m < 2; ++m)
#pragma unroll
            for (int n = 0; n < 2; ++n) acc[qq][m][n] = (f32x4){0.f, 0.f, 0.f, 0.f};

    int srow = tid >> 2, scol = (tid & 3) << 3;
    int ldst = (tid & 0xC0) * 8;
    for (int k0 = 0; k0 < 256; k0 += 32) {
        {
            const ushort* s0 = ctx  + (size_t)(bm + srow) * 256 + k0 + scol;
            const ushort* s1 = h_in + (size_t)(bm + srow) * 256 + k0 + scol;
            __builtin_amdgcn_global_load_lds((gvoid_t*)s0, (lvoid_t*)&lds[ldst], 16, 0, 0);
            __builtin_amdgcn_global_load_lds((gvoid_t*)s1, (lvoid_t*)&lds[2048 + ldst], 16, 0, 0);
#pragma unroll
            for (int qq = 0; qq < 6; ++qq) {
                const ushort* wb = (qq < 3) ? wih : whh;
                int slice = (qq < 3) ? qq : qq - 3;
                const ushort* sv = wb + (size_t)(slice * 256 + ct * 64 + srow) * 256 + k0 + scol;
                __builtin_amdgcn_global_load_lds((gvoid_t*)sv,
                    (lvoid_t*)&lds[(2 + qq) * 2048 + ldst], 16, 0, 0);
            }
        }
        __syncthreads();
        int rl = lane & 15;
        int kc = (lane >> 4) * 8;
        bf16x8 a_c[2], a_h[2];
#pragma unroll
        for (int m = 0; m < 2; ++m) {
            a_c[m] = *reinterpret_cast<const bf16x8*>(&lds[(wr * 32 + m * 16 + rl) * 32 + kc]);
            a_h[m] = *reinterpret_cast<const bf16x8*>(&lds[2048 + (wr * 32 + m * 16 + rl) * 32 + kc]);
        }
#pragma unroll
        for (int qq = 0; qq < 6; ++qq) {
            bf16x8 bw[2];
#pragma unroll
            for (int n = 0; n < 2; ++n)
                bw[n] = *reinterpret_cast<const bf16x8*>(
                    &lds[(2 + qq) * 2048 + (wc * 32 + n * 16 + rl) * 32 + kc]);
#pragma unroll
            for (int m = 0; m < 2; ++m)
#pragma unroll
                for (int n = 0; n < 2; ++n)
                    acc[qq][m][n] = __builtin_amdgcn_mfma_f32_16x16x32_bf16(
                        (qq < 3) ? a_c[m] : a_h[m], bw[n], acc[qq][m][n], 0, 0, 0);
        }
        __syncthreads();
    }

    int rl = lane & 15;
    int r0 = (lane >> 4) * 4;
    float mv[2][4];
    float dswv[2];
    if (TAIL) {
        int b_ = bm >> 9;
        int sbase = bm & 511;
#pragma unroll
        for (int m = 0; m < 2; ++m)
#pragma unroll
            for (int j = 0; j < 4; ++j)
                mv[m][j] = mask[b_ * 512 + sbase + wr * 32 + m * 16 + r0 + j];
#pragma unroll
        for (int n = 0; n < 2; ++n)
            dswv[n] = dsw[ct * 64 + wc * 32 + n * 16 + rl];
    }
    float pm[2] = {0.f, 0.f};
    float ps[2][4] = {{0.f, 0.f, 0.f, 0.f}, {0.f, 0.f, 0.f, 0.f}};

#pragma unroll
    for (int n = 0; n < 2; ++n) {
        int col = ct * 64 + wc * 32 + n * 16 + rl;
        float bir = bih[col], biz = bih[256 + col], bin = bih[512 + col];
        float bhr = bhh[col], bhz = bhh[256 + col], bhn = bhh[512 + col];
#pragma unroll
        for (int m = 0; m < 2; ++m) {
            int row0 = bm + wr * 32 + m * 16 + r0;
#pragma unroll
            for (int j = 0; j < 4; ++j) {
                size_t idx = (size_t)(row0 + j) * 256 + col;
                float r = sigm_fast(acc[0][m][n][j] + bir + acc[3][m][n][j] + bhr);
                float z = sigm_fast(acc[1][m][n][j] + biz + acc[4][m][n][j] + bhz);
                float nn = tanh_fast(acc[2][m][n][j] + bin + r * (acc[5][m][n][j] + bhn));
                float hold = bf2f(h_in[idx]);
                float hh = (1.f - z) * nn + z * hold;
                ushort hb = f2bf(hh);
                h_out[idx] = hb;
                if (TAIL) {
                    float a = fmaxf(bf2f(hb), 0.f);
                    pm[n] = fmaf(a, mv[m][j], pm[n]);
                    ps[m][j] = fmaf(a, dswv[n], ps[m][j]);
                }
            }
        }
    }

    if (TAIL) {
#pragma unroll
        for (int n = 0; n < 2; ++n) {
            float p = pm[n];
            p += __shfl_xor(p, 16);
            p += __shfl_xor(p, 32);
            if (lane < 16) {
                int b_ = bm >> 9;
                int sc = ((bm & 511) >> 5) + wr;
                int col = ct * 64 + wc * 32 + n * 16 + rl;
                pool_part[((size_t)b_ * 16 + sc) * 256 + col] = p;
            }
        }
#pragma unroll
        for (int m = 0; m < 2; ++m)
#pragma unroll
            for (int j = 0; j < 4; ++j) {
                float p = ps[m][j];
                p += __shfl_xor(p, 1);
                p += __shfl_xor(p, 2);
                p += __shfl_xor(p, 4);
                p += __shfl_xor(p, 8);
                if (rl == 0) {
                    int row = bm + wr * 32 + m * 16 + r0 + j;
                    scor_part[(size_t)(ct * 2 + wc) * BS + row] = p;
                }
            }
    }
}

// ---------------- embed (+ fused round-0 alignment dots) ----------------
__global__ __launch_bounds__(256) void embed_kernel(
    const float* __restrict__ amino, const float* __restrict__ embW,
    const float* __restrict__ embB, const float* __restrict__ neighW,
    const float* __restrict__ neighB, const float* __restrict__ alignW,
    ushort* __restrict__ h_bf, ushort* __restrict__ nf_bf,
    float* __restrict__ ca, float* __restrict__ cb)
{
    const int FIN = 26, FPAD = 28, ROWS = 64;
    __shared__ __align__(16) float xs[ROWS][FPAD];
    __shared__ float red1[ROWS][4];
    __shared__ float red2[ROWS][4];
    int tid = threadIdx.x;
    int lane = tid & 63, wv = tid >> 6;
    float wE[FPAD], wN[FPAD];
#pragma unroll
    for (int f = 0; f < FIN; ++f) {
        wE[f] = embW[tid * FIN + f];
        wN[f] = neighW[tid * FIN + f];
    }
    wE[26] = wE[27] = wN[26] = wN[27] = 0.f;
    float b1 = embB[tid], b2 = neighB[tid];
    float w1t = alignW[tid], w2t = alignW[256 + tid];
    int row0 = blockIdx.x * ROWS;
    for (int idx = tid; idx < ROWS * FPAD; idx += 256) {
        int r = idx / FPAD, f = idx - r * FPAD;
        xs[r][f] = (f < FIN) ? amino[(size_t)(row0 + r) * FIN + f] : 0.f;
    }
    __syncthreads();
    for (int r = 0; r < ROWS; ++r) {
        const float4* x4 = reinterpret_cast<const float4*>(xs[r]);
        float a = b1, c = b2;
#pragma unroll
        for (int q = 0; q < 7; ++q) {
            float4 x = x4[q];
            a = fmaf(x.x, wE[4 * q], a);     c = fmaf(x.x, wN[4 * q], c);
            a = fmaf(x.y, wE[4 * q + 1], a); c = fmaf(x.y, wN[4 * q + 1], c);
            a = fmaf(x.z, wE[4 * q + 2], a); c = fmaf(x.z, wN[4 * q + 2], c);
            a = fmaf(x.w, wE[4 * q + 3], a); c = fmaf(x.w, wN[4 * q + 3], c);
        }
        a = a > 0.f ? a : 0.01f * a;
        c = c > 0.f ? c : 0.01f * c;
        size_t idx = (size_t)(row0 + r) * 256 + tid;
        h_bf[idx] = f2bf(a);
        nf_bf[idx] = f2bf(c);
        float p1 = a * w1t, p2 = c * w2t;
#pragma unroll
        for (int off = 32; off > 0; off >>= 1) {
            p1 += __shfl_down(p1, off);
            p2 += __shfl_down(p2, off);
        }
        if (lane == 0) { red1[r][wv] = p1; red2[r][wv] = p2; }
    }
    __syncthreads();
    if (tid < ROWS)
        ca[row0 + tid] = red1[tid][0] + red1[tid][1] + red1[tid][2] + red1[tid][3];
    else if (tid < 2 * ROWS) {
        int r = tid - ROWS;
        cb[row0 + r] = red2[r][0] + red2[r][1] + red2[r][2] + red2[r][3];
    }
}

// attn: 4 rows/block, one wave per row, BRANCHLESS bf16 gather
__global__ __launch_bounds__(256) void attn_kernel(
    const int* __restrict__ deg, const float* __restrict__ ca,
    const float* __restrict__ cbrow, const ushort* __restrict__ act_t,
    const float* __restrict__ alignB, int d,
    ushort* __restrict__ context_bf, int S)
{
    const int KNB = 21;
    int raw = blockIdx.x;
    int bid = (raw & 7) * 512 + (raw >> 3);
    int bs0 = bid * 4;
    int b = bs0 >> 9;
    int tid = threadIdx.x;
    int wv = tid >> 6, lane = tid & 63;
    int bs = bs0 + wv;
    __shared__ float ss[4][KNB];
    __shared__ int   sj[4][KNB];
    if (lane < KNB) {
        int j = deg[bs * KNB + lane];
        float cbv = (j >= 0) ? cbrow[b * S + j] : 0.f;
        float sc = ca[bs] + cbv + alignB[d];
        sc = sc > 0.f ? sc : 0.01f * sc;
        if (j < 0) sc += NEGC;
        sj[wv][lane] = j;
        ss[wv][lane] = sc;
    }
    __syncthreads();
    float mx = -3.4e38f;
#pragma unroll
    for (int k = 0; k < KNB; ++k) mx = fmaxf(mx, ss[wv][k]);
    float se[KNB];
    int js[KNB];
    float sum = 0.f;
#pragma unroll
    for (int k = 0; k < KNB; ++k) {
        int j = sj[wv][k];
        float e = __expf(ss[wv][k] - mx);
        sum += e;
        se[k] = (j >= 0) ? e : 0.f;
        js[k] = (j >= 0) ? j : 0;
    }
    float inv = 1.f / sum;
    const ushort* base = act_t + (size_t)b * S * 256 + lane * 4;
    float a0 = 0.f, a1 = 0.f, a2 = 0.f, a3 = 0.f;
#pragma unroll
    for (int k = 0; k < KNB; ++k) {
        ushort4 v = *reinterpret_cast<const ushort4*>(base + (size_t)js[k] * 256);
        float wk = se[k];
        a0 = fmaf(wk, bf2f(v.x), a0);
        a1 = fmaf(wk, bf2f(v.y), a1);
        a2 = fmaf(wk, bf2f(v.z), a2);
        a3 = fmaf(wk, bf2f(v.w), a3);
    }
    ushort4 o;
    o.x = f2bf(elu_fast(a0 * inv));
    o.y = f2bf(elu_fast(a1 * inv));
    o.z = f2bf(elu_fast(a2 * inv));
    o.w = f2bf(elu_fast(a3 * inv));
    *reinterpret_cast<ushort4*>(&context_bf[(size_t)bs * 256 + lane * 4]) = o;
}

// fused: combine pool partials -> seqfeat + moldot; praw from scor_part (8 slices);
// softmax over S -> wbuf; masked weight sum -> wsumb.
__global__ __launch_bounds__(256) void seqpool_sm_kernel(
    const float* __restrict__ partial, const float* __restrict__ saW,
    const float* __restrict__ scor_part, const float* __restrict__ sab,
    const float* __restrict__ mask,
    float* __restrict__ seqfeat, float* __restrict__ wout,
    float* __restrict__ wsumb, int NC, int S, int BS)
{
    int b = blockIdx.x, tid = threadIdx.x;
    int lane = tid & 63, wv = tid >> 6;
    __shared__ float red[4];
    __shared__ float sw[512];
    __shared__ float r1[4], r2[4], r3[4];
    __shared__ float smd;
    float acc = 0.f;
    for (int c = 0; c < NC; ++c)
        acc += partial[((size_t)b * NC + c) * 256 + tid];
    seqfeat[b * 256 + tid] = acc;
    float am = fmaxf(acc, 0.f);
    float p = am * saW[tid];
#pragma unroll
    for (int off = 32; off > 0; off >>= 1) p += __shfl_down(p, off);
    if (lane == 0) red[wv] = p;
    __syncthreads();
    if (tid == 0) smd = red[0] + red[1] + red[2] + red[3];
    __syncthreads();
    float md = smd, sb = sab[0];
    float lm = -3.4e38f;
    for (int s = tid; s < S; s += 256) {
        int row = b * S + s;
        float praw = 0.f;
#pragma unroll
        for (int sl = 0; sl < 8; ++sl) praw += scor_part[(size_t)sl * BS + row];
        float sc = md + praw + sb;
        sc = sc > 0.f ? sc : 0.01f * sc;
        if (mask[row] == 0.f) sc += NEGC;
        sw[s] = sc;
        lm = fmaxf(lm, sc);
    }
#pragma unroll
    for (int off = 32; off > 0; off >>= 1) lm = fmaxf(lm, __shfl_down(lm, off));
    if (lane == 0) r1[wv] = lm;
    __syncthreads();
    float mx = fmaxf(fmaxf(r1[0], r1[1]), fmaxf(r1[2], r1[3]));
    float ls = 0.f, ms = 0.f;
    for (int s = tid; s < S; s += 256) {
        float e = __expf(sw[s] - mx);
        float em = e * mask[b * S + s];
        sw[s] = em;
        ls += e;
        ms += em;
    }
#pragma unroll
    for (int off = 32; off > 0; off >>= 1) {
        ls += __shfl_down(ls, off);
        ms += __shfl_down(ms, off);
    }
    if (lane == 0) { r2[wv] = ls; r3[wv] = ms; }
    __syncthreads();
    float inv = 1.f / (r2[0] + r2[1] + r2[2] + r2[3]);
    if (tid == 0) wsumb[b] = (r3[0] + r3[1] + r3[2] + r3[3]) * inv;
    for (int s = tid; s < S; s += 256)
        wout[b * S + s] = sw[s] * inv;
}

// weighted act pool partials (act = relu(h))
__global__ __launch_bounds__(256) void wpool_kernel(
    const float* __restrict__ w, const ushort* __restrict__ h,
    float* __restrict__ vpart, int S, int CH)
{
    int bc = blockIdx.x;
    int NC = S / CH;
    int b = bc / NC, c = bc - b * NC;
    int tid = threadIdx.x;
    int s0 = c * CH;
    const ushort* ab = h + ((size_t)b * S + s0) * 256;
    const float* wb = w + b * S + s0;
    float acc = 0.f;
    for (int s = 0; s < CH; ++s)
        acc = fmaf(wb[s], fmaxf(bf2f(ab[(size_t)s * 256 + tid]), 0.f), acc);
    vpart[(size_t)bc * 256 + tid] = acc;
}

// sctx[b,col] = elu( (sum_c vpart[b,c,:]) . seqAttW[col,:] + wsumb[b]*seqAttB[col] )
__global__ __launch_bounds__(256) void sctx_mm_kernel(
    const float* __restrict__ vpart, const float* __restrict__ seqAttW,
    const float* __restrict__ seqAttB, const float* __restrict__ wsumb,
    float* __restrict__ sctx, int NC)
{
    int o = blockIdx.x * 4 + (threadIdx.x >> 6);
    int lane = threadIdx.x & 63;
    int b = o >> 8, col = o & 255;
    const float* wr_ = seqAttW + (size_t)col * 256;
    float p = 0.f;
#pragma unroll
    for (int i = 0; i < 4; ++i) {
        int idx = lane + 64 * i;
        float v = 0.f;
        for (int c = 0; c < 16; ++c)
            v += vpart[((size_t)b * 16 + c) * 256 + idx];
        p = fmaf(v, wr_[idx], p);
    }
#pragma unroll
    for (int off = 32; off > 0; off >>= 1) p += __shfl_down(p, off);
    if (lane == 0)
        sctx[o] = elu_fast(p + wsumb[b] * seqAttB[col]);
}

// sgru matmuls. full=1: both halves; full=0: only gh (gi reused from t=0)
__global__ __launch_bounds__(256) void sgru_mm_kernel(
    const float* __restrict__ x, const float* __restrict__ hseq,
    const float* __restrict__ wih, const float* __restrict__ whh,
    const float* __restrict__ bih, const float* __restrict__ bhh,
    float* __restrict__ g, int full)
{
    int per_b = full ? 1536 : 768;
    int o = blockIdx.x * 4 + (threadIdx.x >> 6);
    int lane = threadIdx.x & 63;
    int b = o / per_b;
    int j = o - b * per_b;
    if (!full) j += 768;
    const float* src; const float* w; const float* bp; int jj;
    if (j < 768) { src = x + b * 256; w = wih; bp = bih; jj = j; }
    else         { src = hseq + b * 256; w = whh; bp = bhh; jj = j - 768; }
    float p = 0.f;
#pragma unroll
    for (int i = 0; i < 4; ++i) {
        int idx = lane + 64 * i;
        p = fmaf(src[idx], w[(size_t)jj * 256 + idx], p);
    }
#pragma unroll
    for (int off = 32; off > 0; off >>= 1) p += __shfl_down(p, off);
    if (lane == 0) g[b * 1536 + j] = p + bp[jj];
}

__global__ __launch_bounds__(256) void sgru_gate_kernel(
    const float* __restrict__ g, float* __restrict__ hseq, float* __restrict__ out)
{
    int b = blockIdx.x, e = threadIdx.x;
    const float* gr = g + b * 1536;
    float r = sigm_fast(gr[e] + gr[768 + e]);
    float z = sigm_fast(gr[256 + e] + gr[1024 + e]);
    float n = tanh_fast(gr[512 + e] + r * gr[1280 + e]);
    float hv = hseq[b * 256 + e];
    float hn = (1.f - z) * n + z * hv;
    hseq[b * 256 + e] = hn;
    out[b * 256 + e] = fmaxf(hn, 0.f);
}

extern "C" void kernel_launch(void* const* d_in, const int* in_sizes, int n_in,
                              void* d_out, int out_size, void* d_ws, size_t ws_size,
                              hipStream_t stream)
{
    const float* amino   = (const float*)d_in[0];
    const int*   deg     = (const int*)  d_in[1];
    const float* mask    = (const float*)d_in[2];
    const float* embW    = (const float*)d_in[3];
    const float* embB    = (const float*)d_in[4];
    const float* neighW  = (const float*)d_in[5];
    const float* neighB  = (const float*)d_in[6];
    const float* alignW  = (const float*)d_in[7];
    const float* alignB  = (const float*)d_in[8];
    const float* attendW = (const float*)d_in[9];
    const float* attendB = (const float*)d_in[10];
    const float* gruWih  = (const float*)d_in[11];
    const float* gruWhh  = (const float*)d_in[12];
    const float* gruBih  = (const float*)d_in[13];
    const float* gruBhh  = (const float*)d_in[14];
    const float* saW     = (const float*)d_in[15];
    const float* saB     = (const float*)d_in[16];
    const float* seqAttW = (const float*)d_in[17];
    const float* seqAttB = (const float*)d_in[18];
    const float* sWih    = (const float*)d_in[19];
    const float* sWhh    = (const float*)d_in[20];
    const float* sBih    = (const float*)d_in[21];
    const float* sBhh    = (const float*)d_in[22];
    float* out = (float*)d_out;

    const int B = 32, S = 512;
    const int BS = B * S;                 // 16384
    const size_t N1 = (size_t)BS * 256;   // 4194304

    ushort* hA     = (ushort*)d_ws;              // N1 (bf16 GRU state, ping)
    ushort* hB     = hA + N1;                    // N1 (pong)
    ushort* nb_bf  = hB + N1;                    // N1 (nf round 0, then context)
    ushort* att_bf = nb_bf + N1;                 // N1 (act_t)
    ushort* attW_bf = att_bf + N1;               // 3*256*256
    ushort* wih_bf  = attW_bf + 3 * 256 * 256;   // 3*768*256
    ushort* whh_bf  = wih_bf + 3 * 768 * 256;
    float* smalls = (float*)(whh_bf + 3 * 768 * 256);
    float* ca    = smalls;            // BS
    float* cb    = ca + BS;           // BS
    float* wbuf  = cb + BS;           // BS
    float* scorp = wbuf + BS;         // 8*BS
    float* seqf  = scorp + 8 * BS;    // B*256
    float* sctx  = seqf + B * 256;    // B*256
    float* wsumb = sctx + B * 256;    // B (pad 256)
    float* g     = wsumb + 256;       // B*1536
    float* part  = g + B * 1536;      // B*16*256
    float* vpart = part + B * 16 * 256; // B*16*256

    const int c0 = (3 * 256 * 256) / 4, c1 = (3 * 768 * 256) / 4,
              c2 = (3 * 768 * 256) / 4;
    cvt3_kernel<<<(c0 + c1 + c2 + 255) / 256, 256, 0, stream>>>(
        attendW, attW_bf, c0, gruWih, wih_bf, c1, gruWhh, whh_bf, c2);

    embed_kernel<<<BS / 64, 256, 0, stream>>>(amino, embW, embB, neighW, neighB, alignW,
                                              hA, nb_bf, ca, cb);

    for (int d = 0; d < 3; ++d) {
        const ushort* h_in  = (d & 1) ? hB : hA;
        ushort*       h_out = (d & 1) ? hA : hB;
        if (d == 0) {
            gemm_dual_kernel<false><<<128 * 2, 256, 0, stream>>>(
                nb_bf, attW_bf, attendB, att_bf, 2, 256,
                (const float*)nullptr, (const float*)nullptr,
                (float*)nullptr, (float*)nullptr);
        } else {
            gemm_dual_kernel<true><<<128 * 2, 256, 0, stream>>>(
                h_in, attW_bf + d * 256 * 256, attendB + d * 256, att_bf, 2, 256,
                alignW + d * 512, alignW + d * 512 + 256, ca, cb);
        }
        attn_kernel<<<BS / 4, 256, 0, stream>>>(deg, ca, cb, att_bf, alignB, d, nb_bf, S);
        if (d < 2) {
            gru_fused_kernel<false><<<1024, 256, 0, stream>>>(
                nb_bf, wih_bf + d * 768 * 256, gruBih + d * 768,
                whh_bf + d * 768 * 256, gruBhh + d * 768, h_in, h_out,
                (const float*)nullptr, (float*)nullptr,
                (const float*)nullptr, (float*)nullptr, BS);
        } else {
            gru_fused_kernel<true><<<1024, 256, 0, stream>>>(
                nb_bf, wih_bf + d * 768 * 256, gruBih + d * 768,
                whh_bf + d * 768 * 256, gruBhh + d * 768, h_in, h_out,
                mask, part, saW + 256, scorp, BS);
        }
    }

    // final h = hB (d=2 writes hB); act = relu(hB)
    seqpool_sm_kernel<<<B, 256, 0, stream>>>(part, saW, scorp, saB, mask,
                                             seqf, wbuf, wsumb, 16, S, BS);
    wpool_kernel<<<B * 16, 256, 0, stream>>>(wbuf, hB, vpart, S, 32);
    sctx_mm_kernel<<<B * 256 / 4, 256, 0, stream>>>(vpart, seqAttW, seqAttB, wsumb, sctx, 16);

    sgru_mm_kernel<<<B * 1536 / 4, 256, 0, stream>>>(sctx, seqf, sWih, sWhh, sBih, sBhh, g, 1);
    sgru_gate_kernel<<<B, 256, 0, stream>>>(g, seqf, out);
    sgru_mm_kernel<<<B * 768 / 4, 256, 0, stream>>>(sctx, seqf, sWih, sWhh, sBih, sBhh, g, 0);
    sgru_gate_kernel<<<B, 256, 0, stream>>>(g, seqf, out);
}